// Round 7
// baseline (437.017 us; speedup 1.0000x reference)
//
#include <hip/hip_runtime.h>
#include <cstdint>

// ---------------------------------------------------------------------------
// GCN: 3 x [ h = relu( Ahat (h W) + b ) ], then log_softmax.
// Round 17: GEMM de-staged. With only ~800 tile-blocks (~3/CU) the old
// {stage 32KB Bs -> barrier -> compute} serialized per block. r15's phase-2
// proved B-frags can be read DIRECTLY from global Wt (every block reads the
// same 32KB -> L1/L2-hot; b = Wt[(nt*16+lr)*D + kk*32 + quad*8], identical
// values to the staged slots). New gemm: 64-thread blocks (1 wave, 32 rows),
// no LDS, no barrier, 3200 blocks. A-path/acc/epilogue verbatim.
// Everything else = r16 (CB=768 histogram CSR, convert folded into hist,
// quarter-wave aggregate). Ledger from r15/r16 subtraction: agg ~205us
// (fabric floor), gemm<0> ~10-12us, CSR+misc ~165us (parallelism-insensitive).
// Lessons kept: no returned global atomics (r11), no agg+gemm fusion
// (r13/r15), no cooperative launch (r14), launch gaps are sub-us (r16).
// edge_index arrives as int32 (harness converts integer inputs).
// ---------------------------------------------------------------------------

#define D 128
#define NBMAX 800      // max dst buckets of 128 nodes (N <= 102400)
#define QCAP 4608      // LDS staging capacity per bucket in finalize
#define CB 768         // histogram/scatter chunks (3 blocks/CU)

typedef __attribute__((ext_vector_type(8))) short bf16x8;
typedef __attribute__((ext_vector_type(4))) float f32x4;

__device__ inline ushort f_to_bf(float f) {
    uint x = __float_as_uint(f);
    return (ushort)((x + 0x7fffu + ((x >> 16) & 1u)) >> 16);   // RNE
}
__device__ inline uint pack_bf2(float a, float b) {
    return (uint)f_to_bf(a) | ((uint)f_to_bf(b) << 16);
}
__device__ inline float bf_lo(uint u) { return __uint_as_float(u << 16); }
__device__ inline float bf_hi(uint u) { return __uint_as_float(u & 0xffff0000u); }

// ---------------- CSR build (histogram sort; LDS atomics only) -------------

// blocks [0,CB): per-chunk dst-bucket histogram. blocks [CB,CB+192): W->Wt.
__global__ void hist_conv(const int* __restrict__ ei, int* __restrict__ hist,
                          int* __restrict__ cursor, int E, int NB,
                          const float* __restrict__ W0, const float* __restrict__ W1,
                          const float* __restrict__ W2, ushort* __restrict__ Wt0,
                          ushort* __restrict__ Wt1, ushort* __restrict__ Wt2) {
    int b = blockIdx.x;
    if (b >= CB) {   // weight conversion tail
        int bb = b - CB;
        int which = bb >> 6;   // 64 blocks (16384 elems) per weight
        int i = (bb & 63) * 256 + threadIdx.x;
        const float* W = which == 0 ? W0 : (which == 1 ? W1 : W2);
        ushort* Wt = which == 0 ? Wt0 : (which == 1 ? Wt1 : Wt2);
        Wt[(i & 127) * D + (i >> 7)] = f_to_bf(W[i]);
        return;
    }
    __shared__ int lh[NBMAX];
    if (b == 0 && threadIdx.x == 0) *cursor = 0;
    for (int i = threadIdx.x; i < NB; i += 256) lh[i] = 0;
    __syncthreads();
    int CE = (E + CB - 1) / CB;
    int e0 = b * CE, e1 = min(e0 + CE, E);
    for (int e = e0 + threadIdx.x; e < e1; e += 256)
        atomicAdd(&lh[ei[(size_t)E + e] >> 7], 1);
    __syncthreads();
    int* hrow = hist + (size_t)b * NB;
    for (int i = threadIdx.x; i < NB; i += 256) hrow[i] = lh[i];
}

// per-bucket exclusive scan over CB chunk counts (3 per thread) + base ticket.
// Bucket regions are disjoint, in ARBITRARY order (fine: consumers use
// per-node (beg,deg) from bd[], never cross-bucket contiguity).
__global__ void col_scan(int* __restrict__ hist, int* __restrict__ btotal,
                         int* __restrict__ bbase, int* __restrict__ cursor, int NB) {
    __shared__ int s[256];
    int g = blockIdx.x, t = threadIdx.x;
    int v[3];
    int sum = 0;
#pragma unroll
    for (int i = 0; i < 3; i++) {
        v[i] = hist[(size_t)(t * 3 + i) * NB + g];
        sum += v[i];
    }
    s[t] = sum;
    __syncthreads();
    for (int off = 1; off < 256; off <<= 1) {
        int u = (t >= off) ? s[t - off] : 0;
        __syncthreads();
        s[t] += u;
        __syncthreads();
    }
    int excl = s[t] - sum;
#pragma unroll
    for (int i = 0; i < 3; i++) {
        hist[(size_t)(t * 3 + i) * NB + g] = excl;
        excl += v[i];
    }
    if (t == 255) { btotal[g] = s[255]; bbase[g] = atomicAdd(cursor, s[255]); }
}

__global__ void scatter_pass(const int* __restrict__ ei, const int* __restrict__ hist,
                             const int* __restrict__ bbase, uint* __restrict__ queue,
                             int E, int NB) {
    __shared__ int loff[NBMAX];
    const int* hrow = hist + (size_t)blockIdx.x * NB;
    for (int i = threadIdx.x; i < NB; i += 256) loff[i] = bbase[i] + hrow[i];
    __syncthreads();
    int CE = (E + CB - 1) / CB;
    int e0 = blockIdx.x * CE, e1 = min(e0 + CE, E);
    for (int e = e0 + threadIdx.x; e < e1; e += 256) {
        int d = ei[(size_t)E + e];
        int s = ei[e];
        int slot = atomicAdd(&loff[d >> 7], 1);       // LDS atomic
        queue[slot] = ((uint)(d & 127) << 17) | (uint)s;   // needs N <= 131072
    }
}

__global__ void finalize_pass(const uint* __restrict__ queue, const int* __restrict__ bbase,
                              const int* __restrict__ btotal, int2* __restrict__ bd,
                              float* __restrict__ dis, int* __restrict__ col, int N) {
    __shared__ uint qs[QCAP];
    __shared__ int cnt[128], pre[128], run[128];
    int g = blockIdx.x, t = threadIdx.x;
    int base = bbase[g], m = btotal[g];
    bool fits = (m <= QCAP);
    if (t < 128) { cnt[t] = 0; run[t] = 0; }
    __syncthreads();
    for (int i = t; i < m; i += 256) {
        uint e = queue[base + i];
        if (fits) qs[i] = e;
        atomicAdd(&cnt[e >> 17], 1);                  // LDS atomic
    }
    __syncthreads();
    if (t < 128) pre[t] = cnt[t];
    __syncthreads();
    for (int off = 1; off < 128; off <<= 1) {
        int u = (t < 128 && t >= off) ? pre[t - off] : 0;
        __syncthreads();
        if (t < 128) pre[t] += u;                     // inclusive scan
        __syncthreads();
    }
    if (t < 128) {
        int node = (g << 7) + t;
        if (node < N) {
            bd[node] = make_int2(base + pre[t] - cnt[t], cnt[t]);
            dis[node] = rsqrtf((float)(cnt[t] + 1));  // self loop -> deg >= 1
        }
    }
    __syncthreads();
    for (int i = t; i < m; i += 256) {
        uint e = fits ? qs[i] : queue[base + i];
        int idx = (int)(e >> 17);
        int r = atomicAdd(&run[idx], 1);              // LDS atomic
        col[base + pre[idx] - cnt[idx] + r] = (int)(e & 0x1FFFFu);
    }
}

// ---------------- GEMM: G[n,128] = dis[row] * (X[n,128] @ W), MFMA ----------
// 1 wave per block, 32 rows, NO LDS, NO barrier. B-frags read directly from
// global Wt (every block reads the same 32KB -> L1/L2-hot):
//   b(nt,kk) = Wt[(nt*16+lr)*D + kk*32 + quad*8 .. +8]
// (identical values to the old staged Bs slots; r15 phase-2 verified.)
template <int F32IN>
__global__ __launch_bounds__(64)
void gemm_mfma(const void* __restrict__ Xv, const ushort* __restrict__ Wt,
               const float* __restrict__ dis, ushort* __restrict__ G, int n) {
    int lane = threadIdx.x;
    int lr = lane & 15, quad = lane >> 4;
    int rowbase = blockIdx.x * 32;

    int ar0 = min(rowbase + lr, n - 1);
    int ar1 = min(rowbase + 16 + lr, n - 1);

    f32x4 acc[2][8];
#pragma unroll
    for (int rt = 0; rt < 2; rt++)
#pragma unroll
        for (int nt = 0; nt < 8; nt++) acc[rt][nt] = (f32x4){0.f, 0.f, 0.f, 0.f};

    const ushort* wb = Wt + lr * D + quad * 8;   // row lr of col-tile 0

#pragma unroll
    for (int kk = 0; kk < 4; kk++) {
        bf16x8 a0, a1;
        if (F32IN) {
            const float* X = (const float*)Xv;
            const float* p0 = X + (size_t)ar0 * D + kk * 32 + quad * 8;
            const float* p1 = X + (size_t)ar1 * D + kk * 32 + quad * 8;
            float4 u0 = ((const float4*)p0)[0], v0 = ((const float4*)p0)[1];
            float4 u1 = ((const float4*)p1)[0], v1 = ((const float4*)p1)[1];
            a0 = (bf16x8){(short)f_to_bf(u0.x), (short)f_to_bf(u0.y), (short)f_to_bf(u0.z), (short)f_to_bf(u0.w),
                          (short)f_to_bf(v0.x), (short)f_to_bf(v0.y), (short)f_to_bf(v0.z), (short)f_to_bf(v0.w)};
            a1 = (bf16x8){(short)f_to_bf(u1.x), (short)f_to_bf(u1.y), (short)f_to_bf(u1.z), (short)f_to_bf(u1.w),
                          (short)f_to_bf(v1.x), (short)f_to_bf(v1.y), (short)f_to_bf(v1.z), (short)f_to_bf(v1.w)};
        } else {
            const ushort* X = (const ushort*)Xv;
            a0 = ((const bf16x8*)(X + (size_t)ar0 * D))[kk * 4 + quad];
            a1 = ((const bf16x8*)(X + (size_t)ar1 * D))[kk * 4 + quad];
        }
#pragma unroll
        for (int nt = 0; nt < 8; nt++) {
            bf16x8 b = *(const bf16x8*)(wb + nt * 16 * D + kk * 32);
            acc[0][nt] = __builtin_amdgcn_mfma_f32_16x16x32_bf16(a0, b, acc[0][nt], 0, 0, 0);
            acc[1][nt] = __builtin_amdgcn_mfma_f32_16x16x32_bf16(a1, b, acc[1][nt], 0, 0, 0);
        }
    }

#pragma unroll
    for (int rt = 0; rt < 2; rt++) {
#pragma unroll
        for (int r = 0; r < 4; r++) {
            int row = rowbase + rt * 16 + quad * 4 + r;
            if (row < n) {
                float dsc = dis[row];
#pragma unroll
                for (int nt = 0; nt < 8; nt++)
                    G[(size_t)row * D + nt * 16 + lr] = f_to_bf(dsc * acc[rt][nt][r]);
            }
        }
    }
}

// ---------------- Aggregation ----------------
// G rows pre-scaled by dis[src]. out[i] = act( dis[i]*(sum G[s] + G[i]) + b ).
// QUARTER-wave (16 lanes x uint4 = 8 bf16) per node; edge loop unrolled x8
// -> 8 KB of gathers in flight per wave. MODE 0: relu->bf16. MODE 1: +lsm->f32.
template <int MODE>
__global__ __launch_bounds__(256)
void aggregate(const ushort* __restrict__ Gv, const float* __restrict__ dis,
               const int2* __restrict__ bd, const int* __restrict__ col,
               const float* __restrict__ bias, void* __restrict__ outv, int n) {
    int node = blockIdx.x * 16 + (threadIdx.x >> 4);
    if (node >= n) return;
    int lane = threadIdx.x & 15;
    const uint4* base = (const uint4*)Gv;

    uint4 u = base[(size_t)node * 16 + lane];
    float a0 = bf_lo(u.x), a1 = bf_hi(u.x), a2 = bf_lo(u.y), a3 = bf_hi(u.y);
    float a4 = bf_lo(u.z), a5 = bf_hi(u.z), a6 = bf_lo(u.w), a7 = bf_hi(u.w);

    int2 be = bd[node];
    int beg = be.x, end = be.x + be.y;
    int j = beg;
    for (; j + 8 <= end; j += 8) {
        uint4 v0 = base[(size_t)col[j + 0] * 16 + lane];
        uint4 v1 = base[(size_t)col[j + 1] * 16 + lane];
        uint4 v2 = base[(size_t)col[j + 2] * 16 + lane];
        uint4 v3 = base[(size_t)col[j + 3] * 16 + lane];
        uint4 v4 = base[(size_t)col[j + 4] * 16 + lane];
        uint4 v5 = base[(size_t)col[j + 5] * 16 + lane];
        uint4 v6 = base[(size_t)col[j + 6] * 16 + lane];
        uint4 v7 = base[(size_t)col[j + 7] * 16 + lane];
        a0 += bf_lo(v0.x) + bf_lo(v1.x) + bf_lo(v2.x) + bf_lo(v3.x)
            + bf_lo(v4.x) + bf_lo(v5.x) + bf_lo(v6.x) + bf_lo(v7.x);
        a1 += bf_hi(v0.x) + bf_hi(v1.x) + bf_hi(v2.x) + bf_hi(v3.x)
            + bf_hi(v4.x) + bf_hi(v5.x) + bf_hi(v6.x) + bf_hi(v7.x);
        a2 += bf_lo(v0.y) + bf_lo(v1.y) + bf_lo(v2.y) + bf_lo(v3.y)
            + bf_lo(v4.y) + bf_lo(v5.y) + bf_lo(v6.y) + bf_lo(v7.y);
        a3 += bf_hi(v0.y) + bf_hi(v1.y) + bf_hi(v2.y) + bf_hi(v3.y)
            + bf_hi(v4.y) + bf_hi(v5.y) + bf_hi(v6.y) + bf_hi(v7.y);
        a4 += bf_lo(v0.z) + bf_lo(v1.z) + bf_lo(v2.z) + bf_lo(v3.z)
            + bf_lo(v4.z) + bf_lo(v5.z) + bf_lo(v6.z) + bf_lo(v7.z);
        a5 += bf_hi(v0.z) + bf_hi(v1.z) + bf_hi(v2.z) + bf_hi(v3.z)
            + bf_hi(v4.z) + bf_hi(v5.z) + bf_hi(v6.z) + bf_hi(v7.z);
        a6 += bf_lo(v0.w) + bf_lo(v1.w) + bf_lo(v2.w) + bf_lo(v3.w)
            + bf_lo(v4.w) + bf_lo(v5.w) + bf_lo(v6.w) + bf_lo(v7.w);
        a7 += bf_hi(v0.w) + bf_hi(v1.w) + bf_hi(v2.w) + bf_hi(v3.w)
            + bf_hi(v4.w) + bf_hi(v5.w) + bf_hi(v6.w) + bf_hi(v7.w);
    }
    for (; j < end; j++) {
        uint4 v = base[(size_t)col[j] * 16 + lane];
        a0 += bf_lo(v.x); a1 += bf_hi(v.x); a2 += bf_lo(v.y); a3 += bf_hi(v.y);
        a4 += bf_lo(v.z); a5 += bf_hi(v.z); a6 += bf_lo(v.w); a7 += bf_hi(v.w);
    }

    float di = dis[node];
    float4 bA = ((const float4*)bias)[lane * 2];
    float4 bB = ((const float4*)bias)[lane * 2 + 1];
    a0 = fmaxf(di * a0 + bA.x, 0.f); a1 = fmaxf(di * a1 + bA.y, 0.f);
    a2 = fmaxf(di * a2 + bA.z, 0.f); a3 = fmaxf(di * a3 + bA.w, 0.f);
    a4 = fmaxf(di * a4 + bB.x, 0.f); a5 = fmaxf(di * a5 + bB.y, 0.f);
    a6 = fmaxf(di * a6 + bB.z, 0.f); a7 = fmaxf(di * a7 + bB.w, 0.f);

    if (MODE == 1) {
        float m = fmaxf(fmaxf(fmaxf(a0, a1), fmaxf(a2, a3)),
                        fmaxf(fmaxf(a4, a5), fmaxf(a6, a7)));
        for (int off = 8; off > 0; off >>= 1) m = fmaxf(m, __shfl_xor(m, off, 16));
        float e = __expf(a0 - m) + __expf(a1 - m) + __expf(a2 - m) + __expf(a3 - m)
                + __expf(a4 - m) + __expf(a5 - m) + __expf(a6 - m) + __expf(a7 - m);
        for (int off = 8; off > 0; off >>= 1) e += __shfl_xor(e, off, 16);
        float ls = m + __logf(e);
        ((float4*)outv)[(size_t)node * 32 + lane * 2]     = make_float4(a0 - ls, a1 - ls, a2 - ls, a3 - ls);
        ((float4*)outv)[(size_t)node * 32 + lane * 2 + 1] = make_float4(a4 - ls, a5 - ls, a6 - ls, a7 - ls);
    } else {
        ((uint4*)outv)[(size_t)node * 16 + lane] =
            make_uint4(pack_bf2(a0, a1), pack_bf2(a2, a3), pack_bf2(a4, a5), pack_bf2(a6, a7));
    }
}

// ---------------- launcher ----------------

static inline size_t align256(size_t x) { return (x + 255) & ~(size_t)255; }

extern "C" void kernel_launch(void* const* d_in, const int* in_sizes, int n_in,
                              void* d_out, int out_size, void* d_ws, size_t ws_size,
                              hipStream_t stream) {
    const float* x  = (const float*)d_in[0];
    const int*   ei = (const int*)d_in[1];      // int32 (harness-converted)
    const float* W0 = (const float*)d_in[2];
    const float* W1 = (const float*)d_in[3];
    const float* W2 = (const float*)d_in[4];
    const float* b0 = (const float*)d_in[5];
    const float* b1 = (const float*)d_in[6];
    const float* b2 = (const float*)d_in[7];
    float* out      = (float*)d_out;

    const int N = in_sizes[0] / D;
    const int E = in_sizes[1] / 2;
    const int NB = (N + 127) >> 7;              // dst buckets (<= NBMAX)

    // workspace (~62 MB)
    char* ws = (char*)d_ws;
    size_t off = 0;
    float*  dis      = (float*)(ws + off);  off = align256(off + (size_t)N * 4);
    int2*   bd       = (int2*)(ws + off);   off = align256(off + (size_t)N * 8);
    int*    hist     = (int*)(ws + off);    off = align256(off + (size_t)CB * NB * 4);
    int*    btotal   = (int*)(ws + off);    off = align256(off + (size_t)NB * 4);
    int*    bbase    = (int*)(ws + off);    off = align256(off + (size_t)NB * 4);
    int*    cursor   = (int*)(ws + off);    off = align256(off + 4);
    ushort* Wt0      = (ushort*)(ws + off); off = align256(off + (size_t)D * D * 2);
    ushort* Wt1      = (ushort*)(ws + off); off = align256(off + (size_t)D * D * 2);
    ushort* Wt2      = (ushort*)(ws + off); off = align256(off + (size_t)D * D * 2);
    int*    col      = (int*)(ws + off);    off = align256(off + (size_t)E * 4);
    ushort* bufA     = (ushort*)(ws + off); off = align256(off + (size_t)N * D * 2);
    ushort* bufB     = (ushort*)(ws + off); off = align256(off + (size_t)N * D * 2);
    ushort* dhead    = (ushort*)d_out;      // 25.6 MB of d_out; dead before final write
    uint*   queue    = (uint*)bufB;         // E*4B = 6.4MB, dead before gemm layer-1
    (void)ws_size;

    // --- CSR build (histogram sort; 3 blocks/CU for the edge passes) ---
    hist_conv<<<CB + 192, 256, 0, stream>>>(ei, hist, cursor, E, NB,
                                            W0, W1, W2, Wt0, Wt1, Wt2);
    col_scan<<<NB, 256, 0, stream>>>(hist, btotal, bbase, cursor, NB);
    scatter_pass<<<CB, 256, 0, stream>>>(ei, hist, bbase, queue, E, NB);
    finalize_pass<<<NB, 256, 0, stream>>>(queue, bbase, btotal, bd, dis, col, N);

    const int gemmBlocks = (N + 31) / 32;       // 1 wave / 32 rows per block
    const int aggBlocks  = (N + 15) / 16;

    // --- layer 0: x(fp32) @ W0 -> dhead; agg -> bufA ---
    gemm_mfma<1><<<gemmBlocks, 64, 0, stream>>>(x, Wt0, dis, dhead, N);
    aggregate<0><<<aggBlocks, 256, 0, stream>>>(dhead, dis, bd, col, b0, bufA, N);
    // --- layer 1: bufA @ W1 -> bufB; agg -> dhead ---
    gemm_mfma<0><<<gemmBlocks, 64, 0, stream>>>(bufA, Wt1, dis, bufB, N);
    aggregate<0><<<aggBlocks, 256, 0, stream>>>(bufB, dis, bd, col, b1, dhead, N);
    // --- layer 2: dhead @ W2 -> bufA; agg + log_softmax -> out ---
    gemm_mfma<0><<<gemmBlocks, 64, 0, stream>>>(dhead, Wt2, dis, bufA, N);
    aggregate<1><<<aggBlocks, 256, 0, stream>>>(bufA, dis, bd, col, b2, out, N);
}

// Round 8
// 416.747 us; speedup vs baseline: 1.0486x; 1.0486x over previous
//
#include <hip/hip_runtime.h>
#include <cstdint>

// ---------------------------------------------------------------------------
// GCN: 3 x [ h = relu( Ahat (h W) + b ) ], then log_softmax.
// Round 18: FINAL revert to r16 (best measured 408.9us). Experiment matrix
// closed: aggregate = random-gather fabric ceiling (2 designs plateau at
// ~3.4TB/s L2-miss path / ~6.5TB/s logical); GEMM must stay Bs-LDS-staged
// (r17 de-stage +28us); agg+gemm fusion loses to barrier-coupled gather
// tails (r13 -24us, r15 break-even); CSR build insensitive to parallelism
// (r16 CB 256->768 = -1.4us), cooperative launch catastrophic (r14 -126us),
// returned global atomics catastrophic (r11 -146us); launch gaps sub-us.
// edge_index arrives as int32 (harness converts integer inputs).
// ---------------------------------------------------------------------------

#define D 128
#define NBMAX 800      // max dst buckets of 128 nodes (N <= 102400)
#define QCAP 4608      // LDS staging capacity per bucket in finalize
#define CB 768         // histogram/scatter chunks (3 blocks/CU)

typedef __attribute__((ext_vector_type(8))) short bf16x8;
typedef __attribute__((ext_vector_type(4))) float f32x4;

__device__ inline ushort f_to_bf(float f) {
    uint x = __float_as_uint(f);
    return (ushort)((x + 0x7fffu + ((x >> 16) & 1u)) >> 16);   // RNE
}
__device__ inline uint pack_bf2(float a, float b) {
    return (uint)f_to_bf(a) | ((uint)f_to_bf(b) << 16);
}
__device__ inline float bf_lo(uint u) { return __uint_as_float(u << 16); }
__device__ inline float bf_hi(uint u) { return __uint_as_float(u & 0xffff0000u); }

// ---------------- CSR build (histogram sort; LDS atomics only) -------------

// blocks [0,CB): per-chunk dst-bucket histogram. blocks [CB,CB+192): W->Wt.
__global__ void hist_conv(const int* __restrict__ ei, int* __restrict__ hist,
                          int* __restrict__ cursor, int E, int NB,
                          const float* __restrict__ W0, const float* __restrict__ W1,
                          const float* __restrict__ W2, ushort* __restrict__ Wt0,
                          ushort* __restrict__ Wt1, ushort* __restrict__ Wt2) {
    int b = blockIdx.x;
    if (b >= CB) {   // weight conversion tail
        int bb = b - CB;
        int which = bb >> 6;   // 64 blocks (16384 elems) per weight
        int i = (bb & 63) * 256 + threadIdx.x;
        const float* W = which == 0 ? W0 : (which == 1 ? W1 : W2);
        ushort* Wt = which == 0 ? Wt0 : (which == 1 ? Wt1 : Wt2);
        Wt[(i & 127) * D + (i >> 7)] = f_to_bf(W[i]);
        return;
    }
    __shared__ int lh[NBMAX];
    if (b == 0 && threadIdx.x == 0) *cursor = 0;
    for (int i = threadIdx.x; i < NB; i += 256) lh[i] = 0;
    __syncthreads();
    int CE = (E + CB - 1) / CB;
    int e0 = b * CE, e1 = min(e0 + CE, E);
    for (int e = e0 + threadIdx.x; e < e1; e += 256)
        atomicAdd(&lh[ei[(size_t)E + e] >> 7], 1);
    __syncthreads();
    int* hrow = hist + (size_t)b * NB;
    for (int i = threadIdx.x; i < NB; i += 256) hrow[i] = lh[i];
}

// per-bucket exclusive scan over CB chunk counts (3 per thread) + base ticket.
// Bucket regions are disjoint, in ARBITRARY order (fine: consumers use
// per-node (beg,deg) from bd[], never cross-bucket contiguity).
__global__ void col_scan(int* __restrict__ hist, int* __restrict__ btotal,
                         int* __restrict__ bbase, int* __restrict__ cursor, int NB) {
    __shared__ int s[256];
    int g = blockIdx.x, t = threadIdx.x;
    int v[3];
    int sum = 0;
#pragma unroll
    for (int i = 0; i < 3; i++) {
        v[i] = hist[(size_t)(t * 3 + i) * NB + g];
        sum += v[i];
    }
    s[t] = sum;
    __syncthreads();
    for (int off = 1; off < 256; off <<= 1) {
        int u = (t >= off) ? s[t - off] : 0;
        __syncthreads();
        s[t] += u;
        __syncthreads();
    }
    int excl = s[t] - sum;
#pragma unroll
    for (int i = 0; i < 3; i++) {
        hist[(size_t)(t * 3 + i) * NB + g] = excl;
        excl += v[i];
    }
    if (t == 255) { btotal[g] = s[255]; bbase[g] = atomicAdd(cursor, s[255]); }
}

__global__ void scatter_pass(const int* __restrict__ ei, const int* __restrict__ hist,
                             const int* __restrict__ bbase, uint* __restrict__ queue,
                             int E, int NB) {
    __shared__ int loff[NBMAX];
    const int* hrow = hist + (size_t)blockIdx.x * NB;
    for (int i = threadIdx.x; i < NB; i += 256) loff[i] = bbase[i] + hrow[i];
    __syncthreads();
    int CE = (E + CB - 1) / CB;
    int e0 = blockIdx.x * CE, e1 = min(e0 + CE, E);
    for (int e = e0 + threadIdx.x; e < e1; e += 256) {
        int d = ei[(size_t)E + e];
        int s = ei[e];
        int slot = atomicAdd(&loff[d >> 7], 1);       // LDS atomic
        queue[slot] = ((uint)(d & 127) << 17) | (uint)s;   // needs N <= 131072
    }
}

__global__ void finalize_pass(const uint* __restrict__ queue, const int* __restrict__ bbase,
                              const int* __restrict__ btotal, int2* __restrict__ bd,
                              float* __restrict__ dis, int* __restrict__ col, int N) {
    __shared__ uint qs[QCAP];
    __shared__ int cnt[128], pre[128], run[128];
    int g = blockIdx.x, t = threadIdx.x;
    int base = bbase[g], m = btotal[g];
    bool fits = (m <= QCAP);
    if (t < 128) { cnt[t] = 0; run[t] = 0; }
    __syncthreads();
    for (int i = t; i < m; i += 256) {
        uint e = queue[base + i];
        if (fits) qs[i] = e;
        atomicAdd(&cnt[e >> 17], 1);                  // LDS atomic
    }
    __syncthreads();
    if (t < 128) pre[t] = cnt[t];
    __syncthreads();
    for (int off = 1; off < 128; off <<= 1) {
        int u = (t < 128 && t >= off) ? pre[t - off] : 0;
        __syncthreads();
        if (t < 128) pre[t] += u;                     // inclusive scan
        __syncthreads();
    }
    if (t < 128) {
        int node = (g << 7) + t;
        if (node < N) {
            bd[node] = make_int2(base + pre[t] - cnt[t], cnt[t]);
            dis[node] = rsqrtf((float)(cnt[t] + 1));  // self loop -> deg >= 1
        }
    }
    __syncthreads();
    for (int i = t; i < m; i += 256) {
        uint e = fits ? qs[i] : queue[base + i];
        int idx = (int)(e >> 17);
        int r = atomicAdd(&run[idx], 1);              // LDS atomic
        col[base + pre[idx] - cnt[idx] + r] = (int)(e & 0x1FFFFu);
    }
}

// ---------------- GEMM: G[n,128] = dis[row] * (X[n,128] @ W), MFMA ----------
// 256 threads = 4 waves; wave computes 32 rows x 128 cols. Wt staged once per
// block into LDS in frag-major swizzled order (lane-contiguous ds_read_b128).
template <int F32IN>
__global__ __launch_bounds__(256)
void gemm_mfma(const void* __restrict__ Xv, const ushort* __restrict__ Wt,
               const float* __restrict__ dis, ushort* __restrict__ G, int n) {
    __shared__ ushort Bs[32 * 64 * 8];   // 32 KB
    int tid = threadIdx.x;
    int wave = tid >> 6, lane = tid & 63;
    int lr = lane & 15, quad = lane >> 4;
    int rowbase = blockIdx.x * 128 + wave * 32;

    for (int s = tid; s < 2048; s += 256) {
        int g = s >> 6, l = s & 63;
        int kk = g >> 3, nt = g & 7;
        int srow = nt * 16 + (l & 15);
        int scol = kk * 32 + (l >> 4) * 8;
        ((uint4*)Bs)[s] = *(const uint4*)(Wt + srow * D + scol);
    }
    __syncthreads();

    int ar0 = min(rowbase + lr, n - 1);
    int ar1 = min(rowbase + 16 + lr, n - 1);

    f32x4 acc[2][8];
#pragma unroll
    for (int rt = 0; rt < 2; rt++)
#pragma unroll
        for (int nt = 0; nt < 8; nt++) acc[rt][nt] = (f32x4){0.f, 0.f, 0.f, 0.f};

#pragma unroll
    for (int kk = 0; kk < 4; kk++) {
        bf16x8 a0, a1;
        if (F32IN) {
            const float* X = (const float*)Xv;
            const float* p0 = X + (size_t)ar0 * D + kk * 32 + quad * 8;
            const float* p1 = X + (size_t)ar1 * D + kk * 32 + quad * 8;
            float4 u0 = ((const float4*)p0)[0], v0 = ((const float4*)p0)[1];
            float4 u1 = ((const float4*)p1)[0], v1 = ((const float4*)p1)[1];
            a0 = (bf16x8){(short)f_to_bf(u0.x), (short)f_to_bf(u0.y), (short)f_to_bf(u0.z), (short)f_to_bf(u0.w),
                          (short)f_to_bf(v0.x), (short)f_to_bf(v0.y), (short)f_to_bf(v0.z), (short)f_to_bf(v0.w)};
            a1 = (bf16x8){(short)f_to_bf(u1.x), (short)f_to_bf(u1.y), (short)f_to_bf(u1.z), (short)f_to_bf(u1.w),
                          (short)f_to_bf(v1.x), (short)f_to_bf(v1.y), (short)f_to_bf(v1.z), (short)f_to_bf(v1.w)};
        } else {
            const ushort* X = (const ushort*)Xv;
            a0 = ((const bf16x8*)(X + (size_t)ar0 * D))[kk * 4 + quad];
            a1 = ((const bf16x8*)(X + (size_t)ar1 * D))[kk * 4 + quad];
        }
#pragma unroll
        for (int nt = 0; nt < 8; nt++) {
            bf16x8 b = ((const bf16x8*)Bs)[(kk * 8 + nt) * 64 + lane];
            acc[0][nt] = __builtin_amdgcn_mfma_f32_16x16x32_bf16(a0, b, acc[0][nt], 0, 0, 0);
            acc[1][nt] = __builtin_amdgcn_mfma_f32_16x16x32_bf16(a1, b, acc[1][nt], 0, 0, 0);
        }
    }

#pragma unroll
    for (int rt = 0; rt < 2; rt++) {
#pragma unroll
        for (int r = 0; r < 4; r++) {
            int row = rowbase + rt * 16 + quad * 4 + r;
            if (row < n) {
                float dsc = dis[row];
#pragma unroll
                for (int nt = 0; nt < 8; nt++)
                    G[(size_t)row * D + nt * 16 + lr] = f_to_bf(dsc * acc[rt][nt][r]);
            }
        }
    }
}

// ---------------- Aggregation ----------------
// G rows pre-scaled by dis[src]. out[i] = act( dis[i]*(sum G[s] + G[i]) + b ).
// QUARTER-wave (16 lanes x uint4 = 8 bf16) per node; edge loop unrolled x8
// -> 8 KB of gathers in flight per wave. MODE 0: relu->bf16. MODE 1: +lsm->f32.
template <int MODE>
__global__ __launch_bounds__(256)
void aggregate(const ushort* __restrict__ Gv, const float* __restrict__ dis,
               const int2* __restrict__ bd, const int* __restrict__ col,
               const float* __restrict__ bias, void* __restrict__ outv, int n) {
    int node = blockIdx.x * 16 + (threadIdx.x >> 4);
    if (node >= n) return;
    int lane = threadIdx.x & 15;
    const uint4* base = (const uint4*)Gv;

    uint4 u = base[(size_t)node * 16 + lane];
    float a0 = bf_lo(u.x), a1 = bf_hi(u.x), a2 = bf_lo(u.y), a3 = bf_hi(u.y);
    float a4 = bf_lo(u.z), a5 = bf_hi(u.z), a6 = bf_lo(u.w), a7 = bf_hi(u.w);

    int2 be = bd[node];
    int beg = be.x, end = be.x + be.y;
    int j = beg;
    for (; j + 8 <= end; j += 8) {
        uint4 v0 = base[(size_t)col[j + 0] * 16 + lane];
        uint4 v1 = base[(size_t)col[j + 1] * 16 + lane];
        uint4 v2 = base[(size_t)col[j + 2] * 16 + lane];
        uint4 v3 = base[(size_t)col[j + 3] * 16 + lane];
        uint4 v4 = base[(size_t)col[j + 4] * 16 + lane];
        uint4 v5 = base[(size_t)col[j + 5] * 16 + lane];
        uint4 v6 = base[(size_t)col[j + 6] * 16 + lane];
        uint4 v7 = base[(size_t)col[j + 7] * 16 + lane];
        a0 += bf_lo(v0.x) + bf_lo(v1.x) + bf_lo(v2.x) + bf_lo(v3.x)
            + bf_lo(v4.x) + bf_lo(v5.x) + bf_lo(v6.x) + bf_lo(v7.x);
        a1 += bf_hi(v0.x) + bf_hi(v1.x) + bf_hi(v2.x) + bf_hi(v3.x)
            + bf_hi(v4.x) + bf_hi(v5.x) + bf_hi(v6.x) + bf_hi(v7.x);
        a2 += bf_lo(v0.y) + bf_lo(v1.y) + bf_lo(v2.y) + bf_lo(v3.y)
            + bf_lo(v4.y) + bf_lo(v5.y) + bf_lo(v6.y) + bf_lo(v7.y);
        a3 += bf_hi(v0.y) + bf_hi(v1.y) + bf_hi(v2.y) + bf_hi(v3.y)
            + bf_hi(v4.y) + bf_hi(v5.y) + bf_hi(v6.y) + bf_hi(v7.y);
        a4 += bf_lo(v0.z) + bf_lo(v1.z) + bf_lo(v2.z) + bf_lo(v3.z)
            + bf_lo(v4.z) + bf_lo(v5.z) + bf_lo(v6.z) + bf_lo(v7.z);
        a5 += bf_hi(v0.z) + bf_hi(v1.z) + bf_hi(v2.z) + bf_hi(v3.z)
            + bf_hi(v4.z) + bf_hi(v5.z) + bf_hi(v6.z) + bf_hi(v7.z);
        a6 += bf_lo(v0.w) + bf_lo(v1.w) + bf_lo(v2.w) + bf_lo(v3.w)
            + bf_lo(v4.w) + bf_lo(v5.w) + bf_lo(v6.w) + bf_lo(v7.w);
        a7 += bf_hi(v0.w) + bf_hi(v1.w) + bf_hi(v2.w) + bf_hi(v3.w)
            + bf_hi(v4.w) + bf_hi(v5.w) + bf_hi(v6.w) + bf_hi(v7.w);
    }
    for (; j < end; j++) {
        uint4 v = base[(size_t)col[j] * 16 + lane];
        a0 += bf_lo(v.x); a1 += bf_hi(v.x); a2 += bf_lo(v.y); a3 += bf_hi(v.y);
        a4 += bf_lo(v.z); a5 += bf_hi(v.z); a6 += bf_lo(v.w); a7 += bf_hi(v.w);
    }

    float di = dis[node];
    float4 bA = ((const float4*)bias)[lane * 2];
    float4 bB = ((const float4*)bias)[lane * 2 + 1];
    a0 = fmaxf(di * a0 + bA.x, 0.f); a1 = fmaxf(di * a1 + bA.y, 0.f);
    a2 = fmaxf(di * a2 + bA.z, 0.f); a3 = fmaxf(di * a3 + bA.w, 0.f);
    a4 = fmaxf(di * a4 + bB.x, 0.f); a5 = fmaxf(di * a5 + bB.y, 0.f);
    a6 = fmaxf(di * a6 + bB.z, 0.f); a7 = fmaxf(di * a7 + bB.w, 0.f);

    if (MODE == 1) {
        float m = fmaxf(fmaxf(fmaxf(a0, a1), fmaxf(a2, a3)),
                        fmaxf(fmaxf(a4, a5), fmaxf(a6, a7)));
        for (int off = 8; off > 0; off >>= 1) m = fmaxf(m, __shfl_xor(m, off, 16));
        float e = __expf(a0 - m) + __expf(a1 - m) + __expf(a2 - m) + __expf(a3 - m)
                + __expf(a4 - m) + __expf(a5 - m) + __expf(a6 - m) + __expf(a7 - m);
        for (int off = 8; off > 0; off >>= 1) e += __shfl_xor(e, off, 16);
        float ls = m + __logf(e);
        ((float4*)outv)[(size_t)node * 32 + lane * 2]     = make_float4(a0 - ls, a1 - ls, a2 - ls, a3 - ls);
        ((float4*)outv)[(size_t)node * 32 + lane * 2 + 1] = make_float4(a4 - ls, a5 - ls, a6 - ls, a7 - ls);
    } else {
        ((uint4*)outv)[(size_t)node * 16 + lane] =
            make_uint4(pack_bf2(a0, a1), pack_bf2(a2, a3), pack_bf2(a4, a5), pack_bf2(a6, a7));
    }
}

// ---------------- launcher ----------------

static inline size_t align256(size_t x) { return (x + 255) & ~(size_t)255; }

extern "C" void kernel_launch(void* const* d_in, const int* in_sizes, int n_in,
                              void* d_out, int out_size, void* d_ws, size_t ws_size,
                              hipStream_t stream) {
    const float* x  = (const float*)d_in[0];
    const int*   ei = (const int*)d_in[1];      // int32 (harness-converted)
    const float* W0 = (const float*)d_in[2];
    const float* W1 = (const float*)d_in[3];
    const float* W2 = (const float*)d_in[4];
    const float* b0 = (const float*)d_in[5];
    const float* b1 = (const float*)d_in[6];
    const float* b2 = (const float*)d_in[7];
    float* out      = (float*)d_out;

    const int N = in_sizes[0] / D;
    const int E = in_sizes[1] / 2;
    const int NB = (N + 127) >> 7;              // dst buckets (<= NBMAX)

    // workspace (~62 MB)
    char* ws = (char*)d_ws;
    size_t off = 0;
    float*  dis      = (float*)(ws + off);  off = align256(off + (size_t)N * 4);
    int2*   bd       = (int2*)(ws + off);   off = align256(off + (size_t)N * 8);
    int*    hist     = (int*)(ws + off);    off = align256(off + (size_t)CB * NB * 4);
    int*    btotal   = (int*)(ws + off);    off = align256(off + (size_t)NB * 4);
    int*    bbase    = (int*)(ws + off);    off = align256(off + (size_t)NB * 4);
    int*    cursor   = (int*)(ws + off);    off = align256(off + 4);
    ushort* Wt0      = (ushort*)(ws + off); off = align256(off + (size_t)D * D * 2);
    ushort* Wt1      = (ushort*)(ws + off); off = align256(off + (size_t)D * D * 2);
    ushort* Wt2      = (ushort*)(ws + off); off = align256(off + (size_t)D * D * 2);
    int*    col      = (int*)(ws + off);    off = align256(off + (size_t)E * 4);
    ushort* bufA     = (ushort*)(ws + off); off = align256(off + (size_t)N * D * 2);
    ushort* bufB     = (ushort*)(ws + off); off = align256(off + (size_t)N * D * 2);
    ushort* dhead    = (ushort*)d_out;      // 25.6 MB of d_out; dead before final write
    uint*   queue    = (uint*)bufB;         // E*4B = 6.4MB, dead before gemm layer-1
    (void)ws_size;

    // --- CSR build (histogram sort; 3 blocks/CU for the edge passes) ---
    hist_conv<<<CB + 192, 256, 0, stream>>>(ei, hist, cursor, E, NB,
                                            W0, W1, W2, Wt0, Wt1, Wt2);
    col_scan<<<NB, 256, 0, stream>>>(hist, btotal, bbase, cursor, NB);
    scatter_pass<<<CB, 256, 0, stream>>>(ei, hist, bbase, queue, E, NB);
    finalize_pass<<<NB, 256, 0, stream>>>(queue, bbase, btotal, bd, dis, col, N);

    const int gemmBlocks = (N + 127) / 128;
    const int aggBlocks  = (N + 15) / 16;

    // --- layer 0: x(fp32) @ W0 -> dhead; agg -> bufA ---
    gemm_mfma<1><<<gemmBlocks, 256, 0, stream>>>(x, Wt0, dis, dhead, N);
    aggregate<0><<<aggBlocks, 256, 0, stream>>>(dhead, dis, bd, col, b0, bufA, N);
    // --- layer 1: bufA @ W1 -> bufB; agg -> dhead ---
    gemm_mfma<0><<<gemmBlocks, 256, 0, stream>>>(bufA, Wt1, dis, bufB, N);
    aggregate<0><<<aggBlocks, 256, 0, stream>>>(bufB, dis, bd, col, b1, dhead, N);
    // --- layer 2: dhead @ W2 -> bufA; agg + log_softmax -> out ---
    gemm_mfma<0><<<gemmBlocks, 256, 0, stream>>>(dhead, Wt2, dis, bufA, N);
    aggregate<1><<<aggBlocks, 256, 0, stream>>>(bufA, dis, bd, col, b2, out, N);
}